// Round 3
// baseline (702.851 us; speedup 1.0000x reference)
//
#include <hip/hip_runtime.h>

#define BATCHN 256
#define TSTEPS 199          // MAX_STEP - 1
#define NQ     1000
#define NROWS  (BATCHN * TSTEPS)   // 50944
#define ROW4   250          // float4 groups per row

typedef float v4f __attribute__((ext_vector_type(4)));

// ws layout (floats): [0..255] masked bce sum per batch, [256..511] masked row count per batch
__global__ void zero_ws_kernel(float* __restrict__ ws) {
    int i = threadIdx.x;
    if (i < 2 * BATCHN) ws[i] = 0.0f;
}

// One 64-lane wave per row; 4 waves (256 threads) per block; no LDS, no barriers.
__global__ __launch_bounds__(256) void main_kernel(
    const float* __restrict__ pred,
    const float* __restrict__ batch,
    float* __restrict__ out,
    float* __restrict__ ws)
{
    const int lane = threadIdx.x & 63;
    const int wib  = threadIdx.x >> 6;
    const int r = blockIdx.x * 4 + wib;          // grid = NROWS/4 exactly
    const int b = r / TSTEPS;
    const int t = r - b * TSTEPS;

    const v4f* p4 = (const v4f*)(pred + (size_t)r * NQ);
    const v4f* g4 = (const v4f*)(batch + ((size_t)b * 200 + t + 1) * NQ);

    v4f p[4], g[4];
    #pragma unroll
    for (int k = 0; k < 4; ++k) {
        const int idx = lane + 64 * k;
        if (k < 3 || idx < ROW4) {
            p[k] = __builtin_nontemporal_load(&p4[idx]);
            g[k] = __builtin_nontemporal_load(&g4[idx]);
        } else {
            p[k] = (v4f)(0.0f);
            g[k] = (v4f)(0.0f);
        }
    }

    float s = 0.0f;
    int any = 0;
    #pragma unroll
    for (int k = 0; k < 4; ++k) {
        #pragma unroll
        for (int j = 0; j < 4; ++j) {
            const float pe = p[k][j];
            const float ge = g[k][j];
            any |= (ge == 1.0f);
            float lp = fmaxf(__logf(pe),        -100.0f);
            float l1 = fmaxf(__logf(1.0f - pe), -100.0f);
            s -= l1 + ge * (lp - l1);   // -(g*lp + (1-g)*l1)
        }
    }
    // loaded zeros in the inactive tail contribute -(log(1)+0) = 0 to s. Safe.

    const unsigned long long bal = __ballot(any != 0);
    const float m = bal ? 1.0f : 0.0f;

    // wave-wide bce sum
    #pragma unroll
    for (int off = 32; off > 0; off >>= 1) s += __shfl_down(s, off);

    float* out_pred = out + 1;
    float* out_gt   = out + 1 + (size_t)NROWS * NQ;
    float* out_mask = out + 1 + 2 * (size_t)NROWS * NQ;

    #pragma unroll
    for (int k = 0; k < 4; ++k) {
        const int idx = lane + 64 * k;
        if (k < 3 || idx < ROW4) {
            const size_t o = (size_t)r * NQ + 4 * (size_t)idx;
            #pragma unroll
            for (int j = 0; j < 4; ++j) {
                __builtin_nontemporal_store(p[k][j] * m, &out_pred[o + j]);
                __builtin_nontemporal_store(g[k][j] * m, &out_gt[o + j]);
            }
        }
    }

    if (lane == 0) {
        __builtin_nontemporal_store(m, &out_mask[r]);
        if (bal) {
            atomicAdd(&ws[b], s);
            atomicAdd(&ws[BATCHN + b], 1.0f);
        }
    }
}

__global__ __launch_bounds__(256) void final_kernel(
    float* __restrict__ out, const float* __restrict__ ws)
{
    const int b = threadIdx.x;  // 0..255, one per batch element
    // cnt >= 1 guaranteed: batch[:,1,0] == 1 so t=0 row is always masked
    float per = ws[b] / (ws[BATCHN + b] * (float)NQ);

    #pragma unroll
    for (int off = 32; off > 0; off >>= 1) per += __shfl_down(per, off);

    __shared__ float ssum[4];
    const int lane = b & 63, wid = b >> 6;
    if (lane == 0) ssum[wid] = per;
    __syncthreads();
    if (b == 0) out[0] = ssum[0] + ssum[1] + ssum[2] + ssum[3];
}

extern "C" void kernel_launch(void* const* d_in, const int* in_sizes, int n_in,
                              void* d_out, int out_size, void* d_ws, size_t ws_size,
                              hipStream_t stream) {
    const float* pred  = (const float*)d_in[0];
    const float* batch = (const float*)d_in[1];
    float* out = (float*)d_out;
    float* ws  = (float*)d_ws;

    zero_ws_kernel<<<1, 512, 0, stream>>>(ws);
    main_kernel<<<NROWS / 4, 256, 0, stream>>>(pred, batch, out, ws);
    final_kernel<<<1, 256, 0, stream>>>(out, ws);
}